// Round 9
// baseline (203.299 us; speedup 1.0000x reference)
//
#include <hip/hip_runtime.h>
#include <math.h>

// Router: x (4,8192,1024) f32, W (64,1024) f32
// out = [ top_idx (32768,2) as float | top_gates (32768,2) | loss (1) ]
// ws  = 64 floats of per-expert prob sums (atomic accumulated)
//
// R9: W broadcast via v_readlane (VALU) instead of LDS ds_read.
// R8 measured DS-bound: 80 ds_read_b128/kg/CU (~960cy) vs 256cy FMA -> 23%
// VALUBusy. W tile per wave = 2KB = 2 float4/lane, loaded cooperatively
// from global (2 coalesced dwordx4/tile/wave), double-buffered in REGISTERS;
// k-loop broadcasts via readlane (immediate lane idx) -> SGPR -> v_fmac.
// DS pipe now carries only x (16 reads/kg/CU). VALU wall ~41us.

constexpr int DMODEL = 1024;
constexpr int NEXP   = 64;
constexpr int BM     = 128;   // tokens per block
constexpr int BK     = 64;    // K per tile
constexpr int NWAVE  = 8;
constexpr int NTOK   = 32768;
constexpr int NTILE  = DMODEL / BK;  // 16

__device__ __forceinline__ void gload16(const float* g, float* l) {
    __builtin_amdgcn_global_load_lds(
        (const __attribute__((address_space(1))) unsigned int*)g,
        (__attribute__((address_space(3))) unsigned int*)l,
        16, 0, 0);
}

__device__ __forceinline__ float rl(float v, int srcl) {
    return __int_as_float(__builtin_amdgcn_readlane(__float_as_int(v), srcl));
}

__global__ __launch_bounds__(512, 1) void router_kernel(
    const float* __restrict__ x, const float* __restrict__ W,
    float* __restrict__ out, float* __restrict__ expert_sums)
{
    // 64 KB: xs double-buffer during k-loop; overlaid epilogue arrays after
    __shared__ __align__(16) char smem[2 * BM * BK * 4];
    auto xs = reinterpret_cast<float (*)[BM][BK]>(smem);          // [2][BM][BK]
    auto lmax = reinterpret_cast<float (*)[BM]>(smem);            // [NWAVE][BM] @0
    auto lsum = reinterpret_cast<float (*)[BM]>(smem + 4096);     // [NWAVE][BM]
    auto ltv  = reinterpret_cast<float (*)[BM][2]>(smem + 8192);  // [NWAVE][BM][2]
    auto lti  = reinterpret_cast<int (*)[BM][2]>(smem + 16384);   // [NWAVE][BM][2]

    const int tid  = threadIdx.x;
    const int lane = tid & 63;
    const int w    = tid >> 6;           // wave id 0..7
    const int tok0 = blockIdx.x * BM;
    const int e0   = w * 8;              // this wave's first expert

    float4 acc0[8], acc1[8];
#pragma unroll
    for (int e = 0; e < 8; ++e) {
        acc0[e] = make_float4(0.f, 0.f, 0.f, 0.f);
        acc1[e] = make_float4(0.f, 0.f, 0.f, 0.f);
    }

    // ---- x staging (R8-proven): wave w stages rows [w*16, w*16+16) ----
    auto stageX = [&](int buf, int tile) {
#pragma unroll
        for (int i = 0; i < 4; ++i) {
            const int r0 = w * 16 + i * 4;
            const int r  = r0 + (lane >> 4);
            const int c  = lane & 15;
            const float* src = x + (size_t)(tok0 + r) * DMODEL + tile * BK
                                 + ((c ^ (r & 15)) << 2);
            float* dst = &xs[buf][r0][0] + (lane << 2);
            gload16(src, dst);
        }
    };

    // ---- W cooperative reg tile: lane l holds kg=l>>2, expert e0+(l&3) ----
    // wA: experts e0..e0+3 ; wB: experts e0+4..e0+7
    const float* wsrc = W + (size_t)(e0 + (lane & 3)) * DMODEL + ((lane >> 2) << 2);

    stageX(0, 0);
    float4 wA = *reinterpret_cast<const float4*>(wsrc);
    float4 wB = *reinterpret_cast<const float4*>(wsrc + 4 * DMODEL);
    __syncthreads();

    const int swb = lane & 15;
    int cur = 0;
    for (int tile = 0; tile < NTILE; ++tile) {
        float4 wAn, wBn;
        if (tile + 1 < NTILE) {
            stageX(cur ^ 1, tile + 1);
            wAn = *reinterpret_cast<const float4*>(wsrc + (tile + 1) * BK);
            wBn = *reinterpret_cast<const float4*>(wsrc + 4 * DMODEL + (tile + 1) * BK);
        }
#pragma unroll
        for (int kg = 0; kg < BK / 4; ++kg) {
            const int sw = (kg ^ swb) << 2;
            const float4 xv0 = *reinterpret_cast<const float4*>(&xs[cur][lane][sw]);
            const float4 xv1 = *reinterpret_cast<const float4*>(&xs[cur][lane + 64][sw]);
#pragma unroll
            for (int e = 0; e < 8; ++e) {
                const int srcl = 4 * kg + (e & 3);   // compile-time immediate
                const float4& wr = (e < 4) ? wA : wB;
                const float w0 = rl(wr.x, srcl);
                const float w1 = rl(wr.y, srcl);
                const float w2 = rl(wr.z, srcl);
                const float w3 = rl(wr.w, srcl);
                acc0[e].x = fmaf(xv0.x, w0, acc0[e].x);
                acc0[e].y = fmaf(xv0.y, w1, acc0[e].y);
                acc0[e].z = fmaf(xv0.z, w2, acc0[e].z);
                acc0[e].w = fmaf(xv0.w, w3, acc0[e].w);
                acc1[e].x = fmaf(xv1.x, w0, acc1[e].x);
                acc1[e].y = fmaf(xv1.y, w1, acc1[e].y);
                acc1[e].z = fmaf(xv1.z, w2, acc1[e].z);
                acc1[e].w = fmaf(xv1.w, w3, acc1[e].w);
            }
        }
        __syncthreads();   // next x tile staged + xs reuse guard
        wA = wAn; wB = wBn;
        cur ^= 1;
    }

    // ---- epilogue: tokens t0 = tok0+lane, t1 = tok0+lane+64 ----
    // (xs dead; lmax/lsum/ltv/lti overlay it — all waves past final barrier)
    float l0[8], l1[8];
    float m0 = -INFINITY, m1 = -INFINITY;
#pragma unroll
    for (int e = 0; e < 8; ++e) {
        l0[e] = (acc0[e].x + acc0[e].y) + (acc0[e].z + acc0[e].w);
        l1[e] = (acc1[e].x + acc1[e].y) + (acc1[e].z + acc1[e].w);
        m0 = fmaxf(m0, l0[e]);
        m1 = fmaxf(m1, l1[e]);
    }
    lmax[w][lane] = m0;
    lmax[w][lane + 64] = m1;
    __syncthreads();

    float g0 = -INFINITY, g1 = -INFINITY;
#pragma unroll
    for (int ww = 0; ww < NWAVE; ++ww) {
        g0 = fmaxf(g0, lmax[ww][lane]);
        g1 = fmaxf(g1, lmax[ww][lane + 64]);
    }

    float p0[8], p1[8];
    float s0 = 0.f, s1 = 0.f;
#pragma unroll
    for (int e = 0; e < 8; ++e) {
        p0[e] = __expf(l0[e] - g0); s0 += p0[e];
        p1[e] = __expf(l1[e] - g1); s1 += p1[e];
    }
    lsum[w][lane] = s0;
    lsum[w][lane + 64] = s1;

    // local top-2 per token over this wave's 8 experts (value desc, index asc)
    {
        float v0 = -INFINITY, v1 = -INFINITY; int i0 = NEXP, i1 = NEXP;
        float u0 = -INFINITY, u1 = -INFINITY; int j0 = NEXP, j1 = NEXP;
#pragma unroll
        for (int e = 0; e < 8; ++e) {
            const int gi = e0 + e;
            float v = l0[e];
            if (v > v0) { v1 = v0; i1 = i0; v0 = v; i0 = gi; }
            else if (v > v1) { v1 = v; i1 = gi; }
            float u = l1[e];
            if (u > u0) { u1 = u0; j1 = j0; u0 = u; j0 = gi; }
            else if (u > u1) { u1 = u; j1 = gi; }
        }
        ltv[w][lane][0] = v0; ltv[w][lane][1] = v1;
        lti[w][lane][0] = i0; lti[w][lane][1] = i1;
        ltv[w][lane + 64][0] = u0; ltv[w][lane + 64][1] = u1;
        lti[w][lane + 64][0] = j0; lti[w][lane + 64][1] = j1;
    }
    __syncthreads();

    float gs0 = 0.f, gs1 = 0.f;
#pragma unroll
    for (int ww = 0; ww < NWAVE; ++ww) {
        gs0 += lsum[ww][lane];
        gs1 += lsum[ww][lane + 64];
    }
    const float inv0 = 1.0f / gs0;
    const float inv1 = 1.0f / gs1;

    // per-expert prob sums over this block's 128 tokens -> 1 atomic per (wave, e)
#pragma unroll
    for (int e = 0; e < 8; ++e) {
        float v = p0[e] * inv0 + p1[e] * inv1;
#pragma unroll
        for (int off = 32; off; off >>= 1) v += __shfl_xor(v, off, 64);
        if (lane == 0) atomicAdd(&expert_sums[e0 + e], v);
    }

    // waves 0-1 merge the 8 waves' candidates and write idx + gates
    if (tid < BM) {
        const int t = tid;
        float bv0 = -INFINITY, bv1 = -INFINITY;
        int   bi0 = NEXP, bi1 = NEXP;
#pragma unroll
        for (int ww = 0; ww < NWAVE; ++ww) {
#pragma unroll
            for (int j = 0; j < 2; ++j) {
                float v  = ltv[ww][t][j];
                int   gi = lti[ww][t][j];
                bool b0 = (v > bv0) || (v == bv0 && gi < bi0);
                if (b0) { bv1 = bv0; bi1 = bi0; bv0 = v; bi0 = gi; }
                else {
                    bool b1 = (v > bv1) || (v == bv1 && gi < bi1);
                    if (b1) { bv1 = v; bi1 = gi; }
                }
            }
        }
        float g     = __expf(bv1 - bv0);
        float denom = 1.0f + g;
        float ga = 1.0f / denom;
        float gb = g / denom;

        size_t tok = (size_t)tok0 + t;
        reinterpret_cast<float2*>(out)[tok]            = make_float2((float)bi0, (float)bi1);
        reinterpret_cast<float2*>(out + 2 * NTOK)[tok] = make_float2(ga, gb);
    }
}

__global__ void loss_kernel(const float* __restrict__ sums, float* __restrict__ out)
{
    const int lane = threadIdx.x;  // 64 threads
    float pv = sums[lane] * (1.0f / (float)NTOK);  // avg_probs[lane]
    float m = pv;
#pragma unroll
    for (int off = 32; off; off >>= 1) m += __shfl_xor(m, off, 64);
    m *= (1.0f / (float)NEXP);
    float d = pv - m;
    float v = d * d;
#pragma unroll
    for (int off = 32; off; off >>= 1) v += __shfl_xor(v, off, 64);
    v *= (1.0f / (float)(NEXP - 1));  // ddof=1
    if (lane == 0) {
        float stdv = sqrtf(v);
        float r = stdv / (m + 1e-6f);
        out[4 * NTOK] = r * r;
    }
}

extern "C" void kernel_launch(void* const* d_in, const int* in_sizes, int n_in,
                              void* d_out, int out_size, void* d_ws, size_t ws_size,
                              hipStream_t stream)
{
    const float* x = (const float*)d_in[0];
    const float* W = (const float*)d_in[1];
    float* out  = (float*)d_out;
    float* sums = (float*)d_ws;

    hipMemsetAsync(d_ws, 0, NEXP * sizeof(float), stream);

    hipLaunchKernelGGL(router_kernel, dim3(NTOK / BM), dim3(512), 0, stream,
                       x, W, out, sums);
    hipLaunchKernelGGL(loss_kernel, dim3(1), dim3(64), 0, stream, sums, out);
}

// Round 10
// 51.583 us; speedup vs baseline: 3.9412x; 3.9412x over previous
//
#include <hip/hip_runtime.h>
#include <math.h>
#include <stdint.h>

// Router: x (4,8192,1024) f32, W (64,1024) f32
// out = [ top_idx (32768,2) as float | top_gates (32768,2) | loss (1) ]
// ws  = 64 floats of per-expert prob sums (atomic accumulated)
//
// R10: MFMA with exact 3-way bf16 split (fp32 = hi+mid+lo, 7-bit chunks).
// 6 passes (hh, hm, mh, hl, mm, lh) accumulate into one fp32 acc; dropped
// terms <= 2^-23 rel (below current kernel's own deviation from ref).
// Rationale (R8/R9 measured): every fp32-VALU broadcast path for W is
// pipe-bound (DS 16B/instr = 82us/block; VMEM TA-bound; SMEM lgkmcnt-bound;
// readlane SGPR-hazard-bound). MFMA's B-fragment ds_read delivers 1KB of
// W per instr — the broadcast happens inside the matrix unit.

constexpr int DMODEL = 1024;
constexpr int NEXP   = 64;
constexpr int BM     = 128;   // tokens per block
constexpr int BK     = 64;    // K per tile
constexpr int NTOK   = 32768;
constexpr int NTILE  = DMODEL / BK;  // 16

// LDS map (bytes):
//   XS  @ 0      : fp32 x tile [2][128][64], chunk-swizzled      (65536)
//   WS  @ 65536  : bf16 W split [2][3 comp][64 e][64 k], swizzled (49152)
//   after k-loop: logits [128][76 f32] overlay @0 (38912)
//                 maxArr[128] @65536, invArr[128] @66048, psum[8][64] @66560
constexpr int XS   = 0;
constexpr int XSB  = 128 * 64 * 4;          // 32768 per buffer
constexpr int WS   = 65536;
constexpr int WSB  = 3 * 64 * 64 * 2;       // 24576 per buffer
constexpr int WCMP = 64 * 64 * 2;           // 8192 per component
constexpr int LSTR = 76 * 4;                // logits row stride (bytes)

typedef __attribute__((ext_vector_type(8))) short short8;
typedef __attribute__((ext_vector_type(4))) float f32x4;

__device__ __forceinline__ void gload16(const float* g, char* l) {
    __builtin_amdgcn_global_load_lds(
        (const __attribute__((address_space(1))) unsigned int*)g,
        (__attribute__((address_space(3))) unsigned int*)l,
        16, 0, 0);
}

// split one fp32 into 3 bf16 (truncation chunks; x = h+m+l exact to 2^-24)
__device__ __forceinline__ void split3(float x, short& h, short& m, short& l) {
    uint32_t u  = __float_as_uint(x);
    uint32_t uh = u & 0xffff0000u;
    float    r  = x - __uint_as_float(uh);
    uint32_t ur = __float_as_uint(r);
    uint32_t um = ur & 0xffff0000u;
    float    r2 = r - __uint_as_float(um);
    h = (short)(uh >> 16);
    m = (short)(um >> 16);
    l = (short)(__float_as_uint(r2) >> 16);
}

__global__ __launch_bounds__(512, 1) void router_kernel(
    const float* __restrict__ x, const float* __restrict__ W,
    float* __restrict__ out, float* __restrict__ expert_sums)
{
    __shared__ __align__(16) char smem[114688];

    const int tid  = threadIdx.x;
    const int lane = tid & 63;
    const int w    = tid >> 6;           // wave id 0..7 (= M-tile)
    const int tok0 = blockIdx.x * BM;

    f32x4 acc[4];
#pragma unroll
    for (int nt = 0; nt < 4; ++nt) acc[nt] = (f32x4){0.f, 0.f, 0.f, 0.f};

    // ---- x staging (R8-proven): wave w stages rows [w*16, w*16+16) ----
    // phys 16B-chunk c of row r holds logical chunk c ^ (r&15)
    auto stageX = [&](int buf, int tile) {
#pragma unroll
        for (int i = 0; i < 4; ++i) {
            const int r0 = w * 16 + i * 4;
            const int r  = r0 + (lane >> 4);
            const int c  = lane & 15;
            const float* src = x + (size_t)(tok0 + r) * DMODEL + tile * BK
                                 + ((c ^ (r & 15)) << 2);
            gload16(src, smem + XS + buf * XSB + r0 * 256 + (lane << 4));
        }
    };

    // ---- W slice -> 3x bf16 LDS (shared across waves) ----
    // thread t owns expert we = t>>3, 8-float chunk wc = t&7 of the k-tile
    const int we  = tid >> 3;
    const int wc  = tid & 7;
    const int wph = wc ^ (we & 7);       // chunk swizzle (read side inverts)
    const float* wgp = W + (size_t)we * DMODEL + wc * 8;

    auto convW = [&](int buf, float4 a, float4 b) {
        short8 sH, sM, sL;
        float v[8] = {a.x, a.y, a.z, a.w, b.x, b.y, b.z, b.w};
#pragma unroll
        for (int j = 0; j < 8; ++j) {
            short h, m, l; split3(v[j], h, m, l);
            sH[j] = h; sM[j] = m; sL[j] = l;
        }
        char* d = smem + WS + buf * WSB + we * 128 + wph * 16;
        *reinterpret_cast<short8*>(d)             = sH;
        *reinterpret_cast<short8*>(d + WCMP)      = sM;
        *reinterpret_cast<short8*>(d + 2 * WCMP)  = sL;
    };

    // prologue: tile 0
    stageX(0, 0);
    {
        float4 a = *reinterpret_cast<const float4*>(wgp);
        float4 b = *reinterpret_cast<const float4*>(wgp + 4);
        convW(0, a, b);
    }
    __syncthreads();

    int buf = 0;
    for (int tile = 0; tile < NTILE; ++tile) {
        float4 wa, wb;
        if (tile + 1 < NTILE) {
            stageX(buf ^ 1, tile + 1);
            wa = *reinterpret_cast<const float4*>(wgp + (tile + 1) * BK);
            wb = *reinterpret_cast<const float4*>(wgp + (tile + 1) * BK + 4);
        }

#pragma unroll
        for (int ks = 0; ks < 2; ++ks) {
            // A: 8 fp32 from xs -> 3 bf16 frags (lane&15 = token row,
            // lane>>4 selects the 8-wide k-group; same map as B below, so
            // any hw k-permutation cancels between A and B)
            const int rl = w * 16 + (lane & 15);
            const int c0 = ks * 8 + (lane >> 4) * 2;
            const char* xrow = smem + XS + buf * XSB + rl * 256;
            const float4 xa = *reinterpret_cast<const float4*>(
                xrow + ((c0 ^ (lane & 15)) << 4));
            const float4 xb = *reinterpret_cast<const float4*>(
                xrow + (((c0 + 1) ^ (lane & 15)) << 4));
            short8 aH, aM, aL;
            {
                float v[8] = {xa.x, xa.y, xa.z, xa.w, xb.x, xb.y, xb.z, xb.w};
#pragma unroll
                for (int j = 0; j < 8; ++j) {
                    short h, m, l; split3(v[j], h, m, l);
                    aH[j] = h; aM[j] = m; aL[j] = l;
                }
            }
#pragma unroll
            for (int nt = 0; nt < 4; ++nt) {
                const int ef = nt * 16 + (lane & 15);
                const int q  = ks * 4 + (lane >> 4);
                const char* wrow = smem + WS + buf * WSB + ef * 128
                                 + ((q ^ (ef & 7)) << 4);
                const short8 bH = *reinterpret_cast<const short8*>(wrow);
                const short8 bM = *reinterpret_cast<const short8*>(wrow + WCMP);
                const short8 bL = *reinterpret_cast<const short8*>(wrow + 2 * WCMP);
                acc[nt] = __builtin_amdgcn_mfma_f32_16x16x32_bf16(aH, bH, acc[nt], 0, 0, 0);
                acc[nt] = __builtin_amdgcn_mfma_f32_16x16x32_bf16(aH, bM, acc[nt], 0, 0, 0);
                acc[nt] = __builtin_amdgcn_mfma_f32_16x16x32_bf16(aM, bH, acc[nt], 0, 0, 0);
                acc[nt] = __builtin_amdgcn_mfma_f32_16x16x32_bf16(aH, bL, acc[nt], 0, 0, 0);
                acc[nt] = __builtin_amdgcn_mfma_f32_16x16x32_bf16(aM, bM, acc[nt], 0, 0, 0);
                acc[nt] = __builtin_amdgcn_mfma_f32_16x16x32_bf16(aL, bH, acc[nt], 0, 0, 0);
            }
        }

        if (tile + 1 < NTILE) convW(buf ^ 1, wa, wb);
        __syncthreads();
        buf ^= 1;
    }

    // ---- write logits [token][expert] to LDS (C/D: col=lane&15, row=(lane>>4)*4+r) ----
#pragma unroll
    for (int nt = 0; nt < 4; ++nt) {
#pragma unroll
        for (int r = 0; r < 4; ++r) {
            const int t = w * 16 + (lane >> 4) * 4 + r;
            const int e = nt * 16 + (lane & 15);
            *reinterpret_cast<float*>(smem + t * LSTR + e * 4) = acc[nt][r];
        }
    }
    __syncthreads();

    float* maxArr = reinterpret_cast<float*>(smem + 65536);
    float* invArr = reinterpret_cast<float*>(smem + 66048);
    float* psum   = reinterpret_cast<float*>(smem + 66560);

    // pass 1: per-token max, softmax denom, top-2, outputs (threads 0..127)
    if (tid < BM) {
        const char* lrow = smem + tid * LSTR;
        float4 L[16];
#pragma unroll
        for (int i = 0; i < 16; ++i)
            L[i] = *reinterpret_cast<const float4*>(lrow + i * 16);

        float mx = -INFINITY;
#pragma unroll
        for (int i = 0; i < 16; ++i)
            mx = fmaxf(mx, fmaxf(fmaxf(L[i].x, L[i].y), fmaxf(L[i].z, L[i].w)));

        float v0 = -INFINITY, v1 = -INFINITY;
        int   i0 = NEXP, i1 = NEXP;
        float s = 0.f;
#pragma unroll
        for (int i = 0; i < 16; ++i) {
            const float vv[4] = {L[i].x, L[i].y, L[i].z, L[i].w};
#pragma unroll
            for (int c = 0; c < 4; ++c) {
                const float v = vv[c];
                const int  gi = i * 4 + c;
                s += __expf(v - mx);
                if (v > v0) { v1 = v0; i1 = i0; v0 = v; i0 = gi; }
                else if (v > v1) { v1 = v; i1 = gi; }
            }
        }
        maxArr[tid] = mx;
        invArr[tid] = 1.0f / s;

        const float q = __expf(v1 - v0);
        const float d = 1.0f + q;
        const size_t tok = (size_t)tok0 + tid;
        reinterpret_cast<float2*>(out)[tok]            = make_float2((float)i0, (float)i1);
        reinterpret_cast<float2*>(out + 2 * NTOK)[tok] = make_float2(1.0f / d, q / d);
    }
    __syncthreads();

    // pass 2: per-expert prob sums (all 512 threads: e = tid&63, grp = tid>>6)
    {
        const int e = tid & 63, grp = tid >> 6;
        float s = 0.f;
#pragma unroll
        for (int i = 0; i < 16; ++i) {
            const int t = grp * 16 + i;
            const float lg = *reinterpret_cast<const float*>(smem + t * LSTR + e * 4);
            s += __expf(lg - maxArr[t]) * invArr[t];
        }
        psum[grp * 64 + e] = s;
    }
    __syncthreads();
    if (tid < 64) {
        float s = 0.f;
#pragma unroll
        for (int g = 0; g < 8; ++g) s += psum[g * 64 + tid];
        atomicAdd(&expert_sums[tid], s);
    }
}

__global__ void loss_kernel(const float* __restrict__ sums, float* __restrict__ out)
{
    const int lane = threadIdx.x;  // 64 threads
    float pv = sums[lane] * (1.0f / (float)NTOK);  // avg_probs[lane]
    float m = pv;
#pragma unroll
    for (int off = 32; off; off >>= 1) m += __shfl_xor(m, off, 64);
    m *= (1.0f / (float)NEXP);
    float d = pv - m;
    float v = d * d;
#pragma unroll
    for (int off = 32; off; off >>= 1) v += __shfl_xor(v, off, 64);
    v *= (1.0f / (float)(NEXP - 1));  // ddof=1
    if (lane == 0) {
        float stdv = sqrtf(v);
        float r = stdv / (m + 1e-6f);
        out[4 * NTOK] = r * r;
    }
}

extern "C" void kernel_launch(void* const* d_in, const int* in_sizes, int n_in,
                              void* d_out, int out_size, void* d_ws, size_t ws_size,
                              hipStream_t stream)
{
    const float* x = (const float*)d_in[0];
    const float* W = (const float*)d_in[1];
    float* out  = (float*)d_out;
    float* sums = (float*)d_ws;

    hipMemsetAsync(d_ws, 0, NEXP * sizeof(float), stream);

    hipLaunchKernelGGL(router_kernel, dim3(NTOK / BM), dim3(512), 0, stream,
                       x, W, out, sums);
    hipLaunchKernelGGL(loss_kernel, dim3(1), dim3(64), 0, stream, sums, out);
}